// Round 6
// baseline (1465.948 us; speedup 1.0000x reference)
//
#include <hip/hip_runtime.h>

#define B_SZ 256
#define F_SZ 4
#define M_SZ 256
#define D_SZ 8192
#define NITER 10

typedef signed char i8;
typedef unsigned long long u64;
typedef signed char c16 __attribute__((ext_vector_type(16)));
typedef int v4i __attribute__((ext_vector_type(4)));

#define NBFM (B_SZ * F_SZ * M_SZ)   // 262144

// ---- workspace layout (bytes) ----
#define OFF_CB    ((size_t)0)          // i8  [F][M][D]      8 MB
#define OFF_CBT   ((size_t)8  << 20)   // i8  [F][D][M]      8 MB
#define OFF_IN8   ((size_t)16 << 20)   // i8  [B][D]         2 MB
#define OFF_CBBT  ((size_t)18 << 20)   // u64 [F][128][M]    1 MB
#define OFF_INB   ((size_t)19 << 20)   // u64 [B][128]       256 KB
#define OFF_ESB   ((size_t)20 << 20)   // u64 [B][F][128]    1 MB  (sign bits, in-place)
#define OFF_EZB   ((size_t)21 << 20)   // u64 [B][F][128]    1 MB  (zero bits, in-place)
#define OFF_SIMX  ((size_t)22 << 20)   // i8  [B*F][768]     768 KB (digit planes)
#define OFF_P1    ((size_t)23 << 20)   // i32 [24][B*F*M]    24 MB  (iter1 partials)
#define OFF_CBTF  OFF_P1               // u64 [F][64][4096]  8 MB   (aliases p1; written after digits1)
#define OFF_S32   ((size_t)47 << 20)   // i32 [F][D]         128 KB (zeroed)
#define OFF_CHG   (OFF_S32 + (size_t)131072)            // int[16] (zeroed)
#define OFF_BAR   (OFF_CHG + (size_t)64)                // int[16] (zeroed)
#define OFF_PDIG  (OFF_BAR + (size_t)64)                // i8 [3][F][D] 96 KB

__device__ __forceinline__ u64 msk8(u64 x) {
  return (((x >> 7) & 0x0101010101010101ull) * 0x0102040810204080ull) >> 56;
}

// device-wide generation barrier for a 256-block persistent kernel
__device__ __forceinline__ void gridbar(int* bar, int t) {
  __syncthreads();
  if (t == 0) {
    __threadfence();
    const int g = __hip_atomic_load(&bar[1], __ATOMIC_RELAXED, __HIP_MEMORY_SCOPE_AGENT);
    const int v = __hip_atomic_fetch_add(&bar[0], 1, __ATOMIC_ACQ_REL, __HIP_MEMORY_SCOPE_AGENT);
    if (v == 255) {
      __hip_atomic_store(&bar[0], 0, __ATOMIC_RELAXED, __HIP_MEMORY_SCOPE_AGENT);
      __hip_atomic_fetch_add(&bar[1], 1, __ATOMIC_RELEASE, __HIP_MEMORY_SCOPE_AGENT);
    } else {
      while (__hip_atomic_load(&bar[1], __ATOMIC_ACQUIRE, __HIP_MEMORY_SCOPE_AGENT) == g)
        __builtin_amdgcn_s_sleep(1);
    }
    __threadfence();
  }
  __syncthreads();
}

// ---------------- fused setup ----------------
// grid 8192 = f(4) x mt(16) x dt(128); tile = 16 m x 64 d

__global__ __launch_bounds__(256) void k_prep_cb(const float* __restrict__ src,
                                                 i8* __restrict__ cb, i8* __restrict__ cbt,
                                                 u64* __restrict__ cbbT, int* __restrict__ S32) {
  __shared__ __align__(16) i8 tile[16][64];
  const int bid = blockIdx.x;
  const int f = bid >> 11;
  const int mt = (bid >> 7) & 15;
  const int dt = bid & 127;
  const int m0 = mt * 16, d0 = dt * 64;
  const int t = threadIdx.x;
  const int mi = t >> 4, c = t & 15;
  const float4 v = *(const float4*)(src + ((size_t)(f * M_SZ + m0 + mi)) * D_SZ + d0 + c * 4);
  char4 cc;
  cc.x = v.x > 0.f ? 1 : -1;
  cc.y = v.y > 0.f ? 1 : -1;
  cc.z = v.z > 0.f ? 1 : -1;
  cc.w = v.w > 0.f ? 1 : -1;
  *(char4*)(cb + ((size_t)(f * M_SZ + m0 + mi)) * D_SZ + d0 + c * 4) = cc;
  *(char4*)&tile[mi][c * 4] = cc;
  __syncthreads();
  if (t < 64) {
    const int dd = t;
    c16 o;
    int ssum = 0;
    #pragma unroll
    for (int mm = 0; mm < 16; ++mm) { const i8 val = tile[mm][dd]; o[mm] = val; ssum += val; }
    *(c16*)(cbt + ((size_t)(f * D_SZ + d0 + dd)) * M_SZ + m0) = o;
    atomicAdd(&S32[f * D_SZ + d0 + dd], ssum);
  } else if (t < 80) {
    const int m = t - 64;
    const u64* row = (const u64*)&tile[m][0];
    u64 w = 0;
    #pragma unroll
    for (int j = 0; j < 8; ++j) w |= msk8(row[j]) << (8 * j);
    cbbT[((size_t)(f * 128 + dt)) * 256 + (m0 + m)] = w;
  }
}

// grid 2048 = bt(16) x dt(128); tile = 16 b x 64 d
__global__ __launch_bounds__(256) void k_prep_in(const float* __restrict__ src,
                                                 i8* __restrict__ dst, u64* __restrict__ inb) {
  __shared__ __align__(16) i8 tile[16][64];
  const int bid = blockIdx.x;
  const int bt = bid >> 7;
  const int dt = bid & 127;
  const int b0 = bt * 16, d0 = dt * 64;
  const int t = threadIdx.x;
  const int mi = t >> 4, c = t & 15;
  const float4 v = *(const float4*)(src + ((size_t)(b0 + mi)) * D_SZ + d0 + c * 4);
  char4 cc;
  cc.x = v.x > 0.f ? 1 : -1;
  cc.y = v.y > 0.f ? 1 : -1;
  cc.z = v.z > 0.f ? 1 : -1;
  cc.w = v.w > 0.f ? 1 : -1;
  *(char4*)(dst + ((size_t)(b0 + mi)) * D_SZ + d0 + c * 4) = cc;
  *(char4*)&tile[mi][c * 4] = cc;
  __syncthreads();
  if (t < 16) {
    const u64* row = (const u64*)&tile[t][0];
    u64 w = 0;
    #pragma unroll
    for (int j = 0; j < 8; ++j) w |= msk8(row[j]) << (8 * j);
    inb[(size_t)(b0 + t) * 128 + dt] = w;
  }
}

// P' = P/8 (exact: each S is even), 3 radix-255 signed digits in [-127,127]
__global__ __launch_bounds__(256) void k_P(const int* __restrict__ S, i8* __restrict__ pdig) {
  const int d = blockIdx.x * 256 + threadIdx.x;     // 8192
  const int s0 = S[d], s1 = S[D_SZ + d], s2 = S[2 * D_SZ + d], s3 = S[3 * D_SZ + d];
  int P[4];
  P[0] = s1 * s2 * s3;
  P[1] = s0 * s2 * s3;
  P[2] = s0 * s1 * s3;
  P[3] = s0 * s1 * s2;
  for (int f = 0; f < 4; ++f) {
    int x = P[f] >> 3;                 // exact (divisible by 8)
    #pragma unroll
    for (int p = 0; p < 2; ++p) {
      const int y = x + 127;
      const int q = (y >= 0) ? (y / 255) : -((-y + 254) / 255);   // floor-style
      const int dg = x - q * 255;      // in [-127,127]
      pdig[((size_t)(p * F_SZ + f)) * D_SZ + d] = (i8)dg;
      x = q;
    }
    pdig[((size_t)(2 * F_SZ + f)) * D_SZ + d] = (i8)x;   // |x| small
  }
}

// ---------------- iteration-1 stage A (MFMA, 3 digit planes of P/8) ----------------
// grid 768: bid = s(8) + 8*( p(3) + 3*( f(4) + 4*ct(8) ) )

__global__ __launch_bounds__(256) void ga2_kernel(
    const i8* __restrict__ in8, const i8* __restrict__ cb,
    const i8* __restrict__ pdig, int* __restrict__ p1)
{
  __shared__ __align__(16) i8 lA[64 * 48];
  __shared__ __align__(16) i8 lB[128 * 48];

  const int bid = blockIdx.x;
  const int s = bid & 7;
  const int r = bid >> 3;
  const int p = r % 3;
  const int q = r / 3;
  const int f = q & 3;
  const int ct = q >> 2;
  const int b0 = (ct >> 1) * 64;
  const int m0 = (ct & 1) * 128;
  const int ksteps = 32;
  const int kbase = s << 10;

  const int t = threadIdx.x;
  const int lane = t & 63;
  const int wv = t >> 6;
  const int wrow = (wv >> 1) * 32;
  const int wcol = (wv & 1) * 64;

  const int arow = t >> 1;
  const int aoff = (t & 1) * 16;
  const i8* pB  = cb   + ((size_t)(f * M_SZ + m0 + arow)) * D_SZ + aoff;
  const i8* pDg = pdig + ((size_t)(p * F_SZ + f)) * D_SZ + aoff;
  const i8* pIn = in8  + (size_t)(b0 + arow) * D_SZ + aoff;

  v4i acc[2][4];
  #pragma unroll
  for (int tr = 0; tr < 2; ++tr)
    #pragma unroll
    for (int tc = 0; tc < 4; ++tc) acc[tr][tc] = 0;

  c16 va = 0, vb = 0;
  {
    const int kk = kbase;
    vb = (*(const c16*)(pB + kk)) * (*(const c16*)(pDg + kk));
    if (t < 128) va = *(const c16*)(pIn + kk);
  }

  for (int j = 0; j < ksteps; ++j) {
    c16 sa = va, sb = vb;
    if (j + 1 < ksteps) {
      const int kk = kbase + (j + 1) * 32;
      vb = (*(const c16*)(pB + kk)) * (*(const c16*)(pDg + kk));
      if (t < 128) va = *(const c16*)(pIn + kk);
    }
    __syncthreads();
    if (t < 128) *(c16*)&lA[arow * 48 + aoff] = sa;
    *(c16*)&lB[arow * 48 + aoff] = sb;
    __syncthreads();

    const int rsel = lane & 15;
    const int kq = (lane >> 4) * 8;
    long af[2], bf[4];
    #pragma unroll
    for (int tr = 0; tr < 2; ++tr) af[tr] = *(const long*)&lA[(wrow + tr * 16 + rsel) * 48 + kq];
    #pragma unroll
    for (int tc = 0; tc < 4; ++tc) bf[tc] = *(const long*)&lB[(wcol + tc * 16 + rsel) * 48 + kq];
    #pragma unroll
    for (int tr = 0; tr < 2; ++tr)
      #pragma unroll
      for (int tc = 0; tc < 4; ++tc)
        acc[tr][tc] = __builtin_amdgcn_mfma_i32_16x16x32_i8(af[tr], bf[tc], acc[tr][tc], 0, 0, 0);
  }

  const int colb = lane & 15;
  const int rowq = (lane >> 4) * 4;
  const size_t obase = (size_t)(p * 8 + s) * NBFM;
  #pragma unroll
  for (int tr = 0; tr < 2; ++tr)
    #pragma unroll
    for (int tc = 0; tc < 4; ++tc)
      #pragma unroll
      for (int rr = 0; rr < 4; ++rr) {
        const int b = b0 + wrow + tr * 16 + rowq + rr;
        const int m = m0 + wcol + tc * 16 + colb;
        p1[obase + (((size_t)(b * F_SZ + f)) << 8) + m] = acc[tr][tc][rr];
      }
}

// recombine 24 slices (3 planes x 8 splits, base 255) -> 3 radix-256 simx digits
__global__ __launch_bounds__(256) void k_digits1(const int* __restrict__ p1, i8* __restrict__ simx) {
  const int idx = blockIdx.x * 256 + threadIdx.x;
  long long g[3];
  #pragma unroll
  for (int p = 0; p < 3; ++p) {
    long long gg = 0;
    #pragma unroll
    for (int s = 0; s < 8; ++s) gg += (long long)p1[(size_t)(p * 8 + s) * NBFM + idx];
    g[p] = gg;
  }
  const long long sim = g[0] + 255LL * g[1] + 65025LL * g[2];
  int x = (int)sim;
  const int r1 = (x + 128) >> 8;
  const int d0 = x - (r1 << 8);
  const int r2 = (r1 + 128) >> 8;
  const int d1 = r1 - (r2 << 8);
  const size_t bf = (size_t)(idx >> 8);
  const int m = idx & 255;
  simx[bf * 768 + m] = (i8)d0;
  simx[bf * 768 + 256 + m] = (i8)d1;
  simx[bf * 768 + 512 + m] = (i8)r2;
}

// ---------------- iteration-1 stage B (NP=3, FIRST) + cbtF write-back ----------------
// grid 1024 = f(4) x ct(256: 4 btiles x 64 dtiles)

__global__ __launch_bounds__(256) void gb_first(
    const i8* __restrict__ simx, const i8* __restrict__ cbt,
    u64* __restrict__ esb, u64* __restrict__ ezb,
    const int* __restrict__ S32, int* __restrict__ changed,
    u64* __restrict__ cbtF)
{
  __shared__ __align__(16) i8 lB[8 * 8 * 64 * 8];   // 32 KB frag-ordered B tile
  __shared__ int chgf;

  const int bid = blockIdx.x;
  const int f = bid & 3;
  const int ct = bid >> 2;
  const int b0 = (ct >> 6) * 64;
  const int d0 = (ct & 63) * 128;

  const int t = threadIdx.x;
  if (t == 0) chgf = 0;
  const int lane = t & 63;
  const int wv = t >> 6;
  const int wrow = (wv >> 1) * 32;
  const int wcol = (wv & 1) * 64;

  {
    const int c = t & 15;
    const int dr0 = t >> 4;
    const int ks = c >> 1;
    const int q0 = (c & 1) * 2;
    #pragma unroll
    for (int i = 0; i < 8; ++i) {
      const int dr = dr0 + i * 16;
      union { c16 v; u64 u[2]; } x;
      x.v = *(const c16*)(cbt + ((size_t)(f * D_SZ + d0 + dr)) * M_SZ + c * 16);
      const int tile = dr >> 4;
      const int col = dr & 15;
      *(u64*)&lB[((((ks * 8 + tile) * 4 + q0) * 16 + col)) * 8] = x.u[0];
      *(u64*)&lB[((((ks * 8 + tile) * 4 + q0 + 1) * 16 + col)) * 8] = x.u[1];
    }
  }
  __syncthreads();

  // one-time: publish frag-ordered tile to global for the persistent loop
  if (bid < 256) {    // exactly the b0==0 blocks: all (f, dtile) combos
    u64* dst = cbtF + ((size_t)(f * 64 + (ct & 63))) * 4096;
    const u64* srcL = (const u64*)lB;
    #pragma unroll
    for (int j = 0; j < 16; ++j) dst[t + j * 256] = srcL[t + j * 256];
  }

  v4i acc[3][2][4];
  #pragma unroll
  for (int pp = 0; pp < 3; ++pp)
    #pragma unroll
    for (int tr = 0; tr < 2; ++tr)
      #pragma unroll
      for (int tc = 0; tc < 4; ++tc) acc[pp][tr][tc] = 0;

  const int rsel = lane & 15;
  const int kq = (lane >> 4) * 8;
  const int tb = wcol >> 4;

  #pragma unroll
  for (int ks = 0; ks < 8; ++ks) {
    long bfv[4];
    #pragma unroll
    for (int tc = 0; tc < 4; ++tc)
      bfv[tc] = *(const long*)&lB[((ks * 8 + tb + tc) * 64 + lane) * 8];
    #pragma unroll
    for (int pp = 0; pp < 3; ++pp) {
      long af[2];
      #pragma unroll
      for (int tr = 0; tr < 2; ++tr) {
        const int row = b0 + wrow + tr * 16 + rsel;
        af[tr] = *(const long*)(simx + ((size_t)(row * 4 + f)) * 768 + pp * 256 + ks * 32 + kq);
      }
      #pragma unroll
      for (int tr = 0; tr < 2; ++tr)
        #pragma unroll
        for (int tc = 0; tc < 4; ++tc)
          acc[pp][tr][tc] = __builtin_amdgcn_mfma_i32_16x16x32_i8(af[tr], bfv[tc], acc[pp][tr][tc], 0, 0, 0);
    }
  }

  bool chl = false;
  const int colb = lane & 15;
  #pragma unroll
  for (int tr = 0; tr < 2; ++tr) {
    u64 bs[4][4], bz[4][4];
    #pragma unroll
    for (int rr = 0; rr < 4; ++rr)
      #pragma unroll
      for (int tc = 0; tc < 4; ++tc) {
        int o = acc[0][tr][tc][rr] + acc[1][tr][tc][rr] * 256 + acc[2][tr][tc][rr] * 65536;
        bs[rr][tc] = __ballot(o < 0);
        bz[rr][tc] = __ballot(o == 0);
        const int sg = (o > 0) - (o < 0);
        const int d = d0 + wcol + tc * 16 + colb;
        chl |= (sg != S32[f * D_SZ + d]);
      }
    u64 ws = 0, wz = 0;
    #pragma unroll
    for (int rl = 0; rl < 16; ++rl) {
      const int g = rl >> 2, rr = rl & 3;
      u64 vs = 0, vz = 0;
      #pragma unroll
      for (int tc = 0; tc < 4; ++tc) {
        vs |= ((bs[rr][tc] >> (g * 16)) & 0xFFFFull) << (tc * 16);
        vz |= ((bz[rr][tc] >> (g * 16)) & 0xFFFFull) << (tc * 16);
      }
      if (lane == rl) { ws = vs; wz = vz; }
    }
    if (lane < 16) {
      const int row = b0 + wrow + tr * 16 + lane;
      const size_t wi = ((size_t)(row * 4 + f)) * 128 + ((d0 + wcol) >> 6);
      esb[wi] = ws;
      ezb[wi] = wz;
    }
  }
  if (chl) atomicOr(&chgf, 1);
  __syncthreads();
  if (t == 0 && chgf) atomicOr(&changed[1], 1);
}

// ---------------- persistent kernel: iterations 2..10 + final argmax ----------------
// grid 256 x 1024 threads (16 waves/CU); each block: 2 phase-A units, 4 phase-B units in parallel

__global__ __launch_bounds__(1024) void k_persist(
    u64* __restrict__ esb, u64* __restrict__ ezb,
    const u64* __restrict__ inb, const u64* __restrict__ cbbT,
    const u64* __restrict__ cbtF, i8* __restrict__ simx,
    int* __restrict__ chg, int* __restrict__ bar, int* __restrict__ out)
{
  __shared__ __align__(16) char lS[25600];   // 2 x 12800-byte unit scratch (phase A / final)
  __shared__ int chgf;

  const int bid = blockIdx.x;
  const int t = threadIdx.x;
  const int lane = t & 63;

  for (int it = 2; it <= NITER; ++it) {
    const bool active =
        __hip_atomic_load(&chg[it - 1], __ATOMIC_RELAXED, __HIP_MEMORY_SCOPE_AGENT) != 0;
    if (t == 0) chgf = 0;

    // ---- phase A: bitwise sims (512 units; 2 per block in parallel, 512 threads each) ----
    if (active) {
      const int sub = t >> 9;             // 0..1
      const int tl = t & 511;
      u64* AL = (u64*)(lS + sub * 12800);            // AL[j*128 + w], j = r*2 + {s,z}
      int* C0 = (int*)(lS + sub * 12800 + 4096);     // [2]
      int* P  = (int*)(lS + sub * 12800 + 4224);     // [(h*2+r)*256 + m]
      const int unit = bid * 2 + sub;
      const int f = unit & 3;
      const int b0 = (unit >> 2) * 2;
      if (tl < 2) C0[tl] = 0;
      __syncthreads();
      if (tl < 256) {
        const int r = tl >> 7, w = tl & 127;
        const int b = b0 + r;
        int ffs[3]; int c = 0;
        for (int ff = 0; ff < 4; ++ff) if (ff != f) ffs[c++] = ff;
        const size_t base = (size_t)b * 512;
        const u64 s = inb[(size_t)b * 128 + w]
          ^ esb[base + ffs[0] * 128 + w] ^ esb[base + ffs[1] * 128 + w] ^ esb[base + ffs[2] * 128 + w];
        const u64 z = ~(ezb[base + ffs[0] * 128 + w] | ezb[base + ffs[1] * 128 + w] | ezb[base + ffs[2] * 128 + w]);
        AL[(r * 2 + 0) * 128 + w] = s;
        AL[(r * 2 + 1) * 128 + w] = z;
        int pcv = (int)__popcll(z);
        #pragma unroll
        for (int off = 32; off >= 1; off >>= 1) pcv += __shfl_down(pcv, off);
        if (lane == 0) atomicAdd(&C0[r], pcv);
      }
      __syncthreads();
      {
        const int h = tl >> 8;            // w-half
        const int m = tl & 255;
        int pa0 = 0, pa1 = 0;
        const u64* pc = cbbT + (size_t)f * 32768 + m;
        const int w0 = h * 64;
        #pragma unroll 4
        for (int w = w0; w < w0 + 64; ++w) {
          const u64 cbw = pc[w * 256];
          pa0 += (int)__popcll((AL[0 * 128 + w] ^ cbw) & AL[1 * 128 + w]);
          pa1 += (int)__popcll((AL[2 * 128 + w] ^ cbw) & AL[3 * 128 + w]);
        }
        P[(h * 2 + 0) * 256 + m] = pa0;
        P[(h * 2 + 1) * 256 + m] = pa1;
      }
      __syncthreads();
      if (tl < 256) {
        const int m = tl;
        const int a0 = P[0 * 256 + m] + P[2 * 256 + m];
        const int a1 = P[1 * 256 + m] + P[3 * 256 + m];
        const int sim0 = C0[0] - 2 * a0;
        const int sim1 = C0[1] - 2 * a1;
        int d1 = (sim0 + 128) >> 8; int d0v = sim0 - (d1 << 8);
        const size_t bf0 = ((size_t)b0 * 4 + f) * 768;
        simx[bf0 + m] = (i8)d0v; simx[bf0 + 256 + m] = (i8)d1;
        d1 = (sim1 + 128) >> 8; d0v = sim1 - (d1 << 8);
        const size_t bf1 = ((size_t)(b0 + 1) * 4 + f) * 768;
        simx[bf1 + m] = (i8)d0v; simx[bf1 + 256 + m] = (i8)d1;
      }
    }
    gridbar(bar, t);

    // ---- phase B: MFMA stage-B + sign + ballot-pack (1024 units; 4 per block, no LDS) ----
    if (active) {
      const int sub = t >> 8;             // 0..3
      const int tl = t & 255;
      const int unit = bid * 4 + sub;
      const int f = unit & 3;
      const int ct = unit >> 2;
      const int b0 = (ct >> 6) * 64;
      const int dt = ct & 63;
      const int wv = tl >> 6;
      const int wrow = (wv >> 1) * 32;
      const int wcol = (wv & 1) * 64;

      v4i acc[2][2][4];
      #pragma unroll
      for (int pp = 0; pp < 2; ++pp)
        #pragma unroll
        for (int tr = 0; tr < 2; ++tr)
          #pragma unroll
          for (int tc = 0; tc < 4; ++tc) acc[pp][tr][tc] = 0;

      const int rsel = lane & 15;
      const int kq = (lane >> 4) * 8;
      const int tb = wcol >> 4;
      const u64* pBF = cbtF + ((size_t)(f * 64 + dt)) * 4096;

      #pragma unroll
      for (int ks = 0; ks < 8; ++ks) {
        long bfv[4];
        #pragma unroll
        for (int tc = 0; tc < 4; ++tc)
          bfv[tc] = (long)pBF[(ks * 8 + tb + tc) * 64 + lane];
        #pragma unroll
        for (int pp = 0; pp < 2; ++pp) {
          long af[2];
          #pragma unroll
          for (int tr = 0; tr < 2; ++tr) {
            const int row = b0 + wrow + tr * 16 + rsel;
            af[tr] = *(const long*)(simx + ((size_t)(row * 4 + f)) * 768 + pp * 256 + ks * 32 + kq);
          }
          #pragma unroll
          for (int tr = 0; tr < 2; ++tr)
            #pragma unroll
            for (int tc = 0; tc < 4; ++tc)
              acc[pp][tr][tc] = __builtin_amdgcn_mfma_i32_16x16x32_i8(af[tr], bfv[tc], acc[pp][tr][tc], 0, 0, 0);
        }
      }

      bool chl = false;
      #pragma unroll
      for (int tr = 0; tr < 2; ++tr) {
        u64 bs[4][4], bz[4][4];
        #pragma unroll
        for (int rr = 0; rr < 4; ++rr)
          #pragma unroll
          for (int tc = 0; tc < 4; ++tc) {
            const int o = acc[0][tr][tc][rr] + acc[1][tr][tc][rr] * 256;
            bs[rr][tc] = __ballot(o < 0);
            bz[rr][tc] = __ballot(o == 0);
          }
        u64 ws = 0, wz = 0;
        #pragma unroll
        for (int rl = 0; rl < 16; ++rl) {
          const int g = rl >> 2, rr = rl & 3;
          u64 vs = 0, vz = 0;
          #pragma unroll
          for (int tc = 0; tc < 4; ++tc) {
            vs |= ((bs[rr][tc] >> (g * 16)) & 0xFFFFull) << (tc * 16);
            vz |= ((bz[rr][tc] >> (g * 16)) & 0xFFFFull) << (tc * 16);
          }
          if (lane == rl) { ws = vs; wz = vz; }
        }
        if (lane < 16) {
          const int row = b0 + wrow + tr * 16 + lane;
          const size_t wi = ((size_t)(row * 4 + f)) * 128 + (dt << 1) + (wcol >> 6);
          chl |= (ws != esb[wi]) | (wz != ezb[wi]);
          esb[wi] = ws;
          ezb[wi] = wz;
        }
      }
      if (chl) atomicOr(&chgf, 1);
      __syncthreads();
      if (t == 0 && chgf) atomicOr(&chg[it], 1);
    }
    gridbar(bar, t);
  }

  // ---- final: sim + argmax + k (512 units; 2 per block) ----
  {
    const int sub = t >> 9;
    const int tl = t & 511;
    u64* AL = (u64*)(lS + sub * 12800);
    int* C0 = (int*)(lS + sub * 12800 + 4096);
    int* P  = (int*)(lS + sub * 12800 + 4224);
    long long* red0 = (long long*)(lS + sub * 12800 + 8320);
    long long* red1 = (long long*)(lS + sub * 12800 + 10368);
    const int unit = bid * 2 + sub;
    const int f = unit & 3;
    const int b0 = (unit >> 2) * 2;
    if (tl < 2) C0[tl] = 0;
    __syncthreads();
    if (tl < 256) {
      const int r = tl >> 7, w = tl & 127;
      const int b = b0 + r;
      const size_t a = ((size_t)b * 4 + f) * 128 + w;
      const u64 s = esb[a];
      const u64 z = ~ezb[a];
      AL[(r * 2 + 0) * 128 + w] = s;
      AL[(r * 2 + 1) * 128 + w] = z;
      int pcv = (int)__popcll(z);
      #pragma unroll
      for (int off = 32; off >= 1; off >>= 1) pcv += __shfl_down(pcv, off);
      if (lane == 0) atomicAdd(&C0[r], pcv);
    }
    __syncthreads();
    {
      const int h = tl >> 8;
      const int m = tl & 255;
      int pa0 = 0, pa1 = 0;
      const u64* pc = cbbT + (size_t)f * 32768 + m;
      const int w0 = h * 64;
      #pragma unroll 4
      for (int w = w0; w < w0 + 64; ++w) {
        const u64 cbw = pc[w * 256];
        pa0 += (int)__popcll((AL[0 * 128 + w] ^ cbw) & AL[1 * 128 + w]);
        pa1 += (int)__popcll((AL[2 * 128 + w] ^ cbw) & AL[3 * 128 + w]);
      }
      P[(h * 2 + 0) * 256 + m] = pa0;
      P[(h * 2 + 1) * 256 + m] = pa1;
    }
    __syncthreads();
    if (tl < 256) {
      const int m = tl;
      const int a0 = P[0 * 256 + m] + P[2 * 256 + m];
      const int a1 = P[1 * 256 + m] + P[3 * 256 + m];
      const int sim0 = C0[0] - 2 * a0;
      const int sim1 = C0[1] - 2 * a1;
      red0[m] = ((long long)sim0 << 32) | (long long)(unsigned)(255 - m);
      red1[m] = ((long long)sim1 << 32) | (long long)(unsigned)(255 - m);
    }
    __syncthreads();
    for (int s2 = 128; s2 > 0; s2 >>= 1) {
      if (tl < s2) {
        if (red0[tl + s2] > red0[tl]) red0[tl] = red0[tl + s2];
        if (red1[tl + s2] > red1[tl]) red1[tl] = red1[tl + s2];
      }
      __syncthreads();
    }
    if (tl == 0) {
      out[b0 * 4 + f] = 255 - (int)(red0[0] & 0xFFFF);
      out[(b0 + 1) * 4 + f] = 255 - (int)(red1[0] & 0xFFFF);
      if (unit == 0) {
        int k = NITER;
        for (int i = 1; i <= NITER; ++i)
          if (__hip_atomic_load(&chg[i], __ATOMIC_RELAXED, __HIP_MEMORY_SCOPE_AGENT) == 0) { k = i; break; }
        out[B_SZ * F_SZ] = k;
      }
    }
  }
}

// ---------------- host ----------------

extern "C" void kernel_launch(void* const* d_in, const int* in_sizes, int n_in,
                              void* d_out, int out_size, void* d_ws, size_t ws_size,
                              hipStream_t stream) {
  const float* f_in = (const float*)d_in[0];   // [B][D]
  const float* f_cb = (const float*)d_in[1];   // [F][M][D]
  int* out = (int*)d_out;
  char* ws = (char*)d_ws;

  i8*  cb8  = (i8*)(ws + OFF_CB);
  i8*  cbt8 = (i8*)(ws + OFF_CBT);
  i8*  in8  = (i8*)(ws + OFF_IN8);
  u64* cbbT = (u64*)(ws + OFF_CBBT);
  u64* inb  = (u64*)(ws + OFF_INB);
  u64* esb  = (u64*)(ws + OFF_ESB);
  u64* ezb  = (u64*)(ws + OFF_EZB);
  i8*  simx = (i8*)(ws + OFF_SIMX);
  int* p1   = (int*)(ws + OFF_P1);
  u64* cbtF = (u64*)(ws + OFF_CBTF);   // aliases p1 (p1 dead after k_digits1)
  int* S32  = (int*)(ws + OFF_S32);
  int* chg  = (int*)(ws + OFF_CHG);
  int* bar  = (int*)(ws + OFF_BAR);
  i8*  pdig = (i8*)(ws + OFF_PDIG);

  // zero S32 (atomic target) + chg flags + barrier state in one memset
  hipMemsetAsync(ws + OFF_S32, 0, 131072 + 128, stream);
  k_prep_cb<<<dim3(8192), dim3(256), 0, stream>>>(f_cb, cb8, cbt8, cbbT, S32);
  k_prep_in<<<dim3(2048), dim3(256), 0, stream>>>(f_in, in8, inb);
  k_P<<<dim3(32), dim3(256), 0, stream>>>(S32, pdig);

  // iteration 1 (big-integer est0 via P/8 digit planes, MFMA)
  ga2_kernel<<<dim3(768), dim3(256), 0, stream>>>(in8, cb8, pdig, p1);
  k_digits1<<<dim3(1024), dim3(256), 0, stream>>>(p1, simx);
  gb_first<<<dim3(1024), dim3(256), 0, stream>>>(simx, cbt8, esb, ezb, S32, chg, cbtF);

  // iterations 2..10 + final argmax in one persistent kernel (256 blocks x 1024 thr)
  k_persist<<<dim3(256), dim3(1024), 0, stream>>>(esb, ezb, inb, cbbT, cbtF, simx, chg, bar, out);
}

// Round 7
// 1320.296 us; speedup vs baseline: 1.1103x; 1.1103x over previous
//
#include <hip/hip_runtime.h>

#define B_SZ 256
#define F_SZ 4
#define M_SZ 256
#define D_SZ 8192
#define NITER 10

typedef signed char i8;
typedef unsigned long long u64;
typedef signed char c16 __attribute__((ext_vector_type(16)));
typedef int v4i __attribute__((ext_vector_type(4)));

#define NBFM (B_SZ * F_SZ * M_SZ)   // 262144

// ---- workspace layout (bytes) ----
#define OFF_CB    ((size_t)0)          // i8  [F][M][D]      8 MB
#define OFF_CBT   ((size_t)8  << 20)   // i8  [F][D][M]      8 MB
#define OFF_IN8   ((size_t)16 << 20)   // i8  [B][D]         2 MB
#define OFF_CBBT  ((size_t)18 << 20)   // u64 [F][128][M]    1 MB
#define OFF_INB   ((size_t)19 << 20)   // u64 [B][128]       256 KB
#define OFF_ESB   ((size_t)20 << 20)   // u64 [B][F][128]    1 MB  (sign bits, in-place)
#define OFF_EZB   ((size_t)21 << 20)   // u64 [B][F][128]    1 MB  (zero bits, in-place)
#define OFF_SIMX  ((size_t)22 << 20)   // i8  [B*F][768]     768 KB (digit planes)
#define OFF_P1    ((size_t)23 << 20)   // i32 [24][B*F*M]    24 MB  (iter1 partials)
#define OFF_CBTF  OFF_P1               // u64 [F][64][4096]  8 MB   (aliases p1; written by gb_first)
#define OFF_S32   ((size_t)47 << 20)   // i32 [F][D]         128 KB (zeroed)
#define OFF_CHG   (OFF_S32 + (size_t)131072)            // int[16] (zeroed)
#define OFF_BAR   (OFF_CHG + (size_t)64)                // int[16] (zeroed)
#define OFF_PDIG  (OFF_BAR + (size_t)64)                // i8 [3][F][D] 96 KB

__device__ __forceinline__ u64 msk8(u64 x) {
  return (((x >> 7) & 0x0101010101010101ull) * 0x0102040810204080ull) >> 56;
}

// device-wide generation barrier for a 256-block persistent kernel
__device__ __forceinline__ void gridbar(int* bar, int t) {
  __syncthreads();
  if (t == 0) {
    __threadfence();
    const int g = __hip_atomic_load(&bar[1], __ATOMIC_RELAXED, __HIP_MEMORY_SCOPE_AGENT);
    const int v = __hip_atomic_fetch_add(&bar[0], 1, __ATOMIC_ACQ_REL, __HIP_MEMORY_SCOPE_AGENT);
    if (v == 255) {
      __hip_atomic_store(&bar[0], 0, __ATOMIC_RELAXED, __HIP_MEMORY_SCOPE_AGENT);
      __hip_atomic_fetch_add(&bar[1], 1, __ATOMIC_RELEASE, __HIP_MEMORY_SCOPE_AGENT);
    } else {
      while (__hip_atomic_load(&bar[1], __ATOMIC_ACQUIRE, __HIP_MEMORY_SCOPE_AGENT) == g)
        __builtin_amdgcn_s_sleep(1);
    }
    __threadfence();
  }
  __syncthreads();
}

// ---------------- fused setup ----------------
// grid 8192 = f(4) x mt(16) x dt(128); tile = 16 m x 64 d

__global__ __launch_bounds__(256) void k_prep_cb(const float* __restrict__ src,
                                                 i8* __restrict__ cb, i8* __restrict__ cbt,
                                                 u64* __restrict__ cbbT, int* __restrict__ S32) {
  __shared__ __align__(16) i8 tile[16][64];
  const int bid = blockIdx.x;
  const int f = bid >> 11;
  const int mt = (bid >> 7) & 15;
  const int dt = bid & 127;
  const int m0 = mt * 16, d0 = dt * 64;
  const int t = threadIdx.x;
  const int mi = t >> 4, c = t & 15;
  const float4 v = *(const float4*)(src + ((size_t)(f * M_SZ + m0 + mi)) * D_SZ + d0 + c * 4);
  char4 cc;
  cc.x = v.x > 0.f ? 1 : -1;
  cc.y = v.y > 0.f ? 1 : -1;
  cc.z = v.z > 0.f ? 1 : -1;
  cc.w = v.w > 0.f ? 1 : -1;
  *(char4*)(cb + ((size_t)(f * M_SZ + m0 + mi)) * D_SZ + d0 + c * 4) = cc;
  *(char4*)&tile[mi][c * 4] = cc;
  __syncthreads();
  if (t < 64) {
    const int dd = t;
    c16 o;
    int ssum = 0;
    #pragma unroll
    for (int mm = 0; mm < 16; ++mm) { const i8 val = tile[mm][dd]; o[mm] = val; ssum += val; }
    *(c16*)(cbt + ((size_t)(f * D_SZ + d0 + dd)) * M_SZ + m0) = o;
    atomicAdd(&S32[f * D_SZ + d0 + dd], ssum);
  } else if (t < 80) {
    const int m = t - 64;
    const u64* row = (const u64*)&tile[m][0];
    u64 w = 0;
    #pragma unroll
    for (int j = 0; j < 8; ++j) w |= msk8(row[j]) << (8 * j);
    cbbT[((size_t)(f * 128 + dt)) * 256 + (m0 + m)] = w;
  }
}

// grid 2048 = bt(16) x dt(128); tile = 16 b x 64 d
__global__ __launch_bounds__(256) void k_prep_in(const float* __restrict__ src,
                                                 i8* __restrict__ dst, u64* __restrict__ inb) {
  __shared__ __align__(16) i8 tile[16][64];
  const int bid = blockIdx.x;
  const int bt = bid >> 7;
  const int dt = bid & 127;
  const int b0 = bt * 16, d0 = dt * 64;
  const int t = threadIdx.x;
  const int mi = t >> 4, c = t & 15;
  const float4 v = *(const float4*)(src + ((size_t)(b0 + mi)) * D_SZ + d0 + c * 4);
  char4 cc;
  cc.x = v.x > 0.f ? 1 : -1;
  cc.y = v.y > 0.f ? 1 : -1;
  cc.z = v.z > 0.f ? 1 : -1;
  cc.w = v.w > 0.f ? 1 : -1;
  *(char4*)(dst + ((size_t)(b0 + mi)) * D_SZ + d0 + c * 4) = cc;
  *(char4*)&tile[mi][c * 4] = cc;
  __syncthreads();
  if (t < 16) {
    const u64* row = (const u64*)&tile[t][0];
    u64 w = 0;
    #pragma unroll
    for (int j = 0; j < 8; ++j) w |= msk8(row[j]) << (8 * j);
    inb[(size_t)(b0 + t) * 128 + dt] = w;
  }
}

// P' = P/8 (exact: each S is even), 3 radix-255 signed digits in [-127,127]
__global__ __launch_bounds__(256) void k_P(const int* __restrict__ S, i8* __restrict__ pdig) {
  const int d = blockIdx.x * 256 + threadIdx.x;     // 8192
  const int s0 = S[d], s1 = S[D_SZ + d], s2 = S[2 * D_SZ + d], s3 = S[3 * D_SZ + d];
  int P[4];
  P[0] = s1 * s2 * s3;
  P[1] = s0 * s2 * s3;
  P[2] = s0 * s1 * s3;
  P[3] = s0 * s1 * s2;
  for (int f = 0; f < 4; ++f) {
    int x = P[f] >> 3;                 // exact (divisible by 8)
    #pragma unroll
    for (int p = 0; p < 2; ++p) {
      const int y = x + 127;
      const int q = (y >= 0) ? (y / 255) : -((-y + 254) / 255);   // floor-style
      const int dg = x - q * 255;      // in [-127,127]
      pdig[((size_t)(p * F_SZ + f)) * D_SZ + d] = (i8)dg;
      x = q;
    }
    pdig[((size_t)(2 * F_SZ + f)) * D_SZ + d] = (i8)x;   // |x| small
  }
}

// ---------------- iteration-1 stage A (MFMA, 3 digit planes of P/8) ----------------
// grid 768: bid = s(8) + 8*( p(3) + 3*( f(4) + 4*ct(8) ) )

__global__ __launch_bounds__(256) void ga2_kernel(
    const i8* __restrict__ in8, const i8* __restrict__ cb,
    const i8* __restrict__ pdig, int* __restrict__ p1)
{
  __shared__ __align__(16) i8 lA[64 * 48];
  __shared__ __align__(16) i8 lB[128 * 48];

  const int bid = blockIdx.x;
  const int s = bid & 7;
  const int r = bid >> 3;
  const int p = r % 3;
  const int q = r / 3;
  const int f = q & 3;
  const int ct = q >> 2;
  const int b0 = (ct >> 1) * 64;
  const int m0 = (ct & 1) * 128;
  const int ksteps = 32;
  const int kbase = s << 10;

  const int t = threadIdx.x;
  const int lane = t & 63;
  const int wv = t >> 6;
  const int wrow = (wv >> 1) * 32;
  const int wcol = (wv & 1) * 64;

  const int arow = t >> 1;
  const int aoff = (t & 1) * 16;
  const i8* pB  = cb   + ((size_t)(f * M_SZ + m0 + arow)) * D_SZ + aoff;
  const i8* pDg = pdig + ((size_t)(p * F_SZ + f)) * D_SZ + aoff;
  const i8* pIn = in8  + (size_t)(b0 + arow) * D_SZ + aoff;

  v4i acc[2][4];
  #pragma unroll
  for (int tr = 0; tr < 2; ++tr)
    #pragma unroll
    for (int tc = 0; tc < 4; ++tc) acc[tr][tc] = 0;

  c16 va = 0, vb = 0;
  {
    const int kk = kbase;
    vb = (*(const c16*)(pB + kk)) * (*(const c16*)(pDg + kk));
    if (t < 128) va = *(const c16*)(pIn + kk);
  }

  for (int j = 0; j < ksteps; ++j) {
    c16 sa = va, sb = vb;
    if (j + 1 < ksteps) {
      const int kk = kbase + (j + 1) * 32;
      vb = (*(const c16*)(pB + kk)) * (*(const c16*)(pDg + kk));
      if (t < 128) va = *(const c16*)(pIn + kk);
    }
    __syncthreads();
    if (t < 128) *(c16*)&lA[arow * 48 + aoff] = sa;
    *(c16*)&lB[arow * 48 + aoff] = sb;
    __syncthreads();

    const int rsel = lane & 15;
    const int kq = (lane >> 4) * 8;
    long af[2], bf[4];
    #pragma unroll
    for (int tr = 0; tr < 2; ++tr) af[tr] = *(const long*)&lA[(wrow + tr * 16 + rsel) * 48 + kq];
    #pragma unroll
    for (int tc = 0; tc < 4; ++tc) bf[tc] = *(const long*)&lB[(wcol + tc * 16 + rsel) * 48 + kq];
    #pragma unroll
    for (int tr = 0; tr < 2; ++tr)
      #pragma unroll
      for (int tc = 0; tc < 4; ++tc)
        acc[tr][tc] = __builtin_amdgcn_mfma_i32_16x16x32_i8(af[tr], bf[tc], acc[tr][tc], 0, 0, 0);
  }

  const int colb = lane & 15;
  const int rowq = (lane >> 4) * 4;
  const size_t obase = (size_t)(p * 8 + s) * NBFM;
  #pragma unroll
  for (int tr = 0; tr < 2; ++tr)
    #pragma unroll
    for (int tc = 0; tc < 4; ++tc)
      #pragma unroll
      for (int rr = 0; rr < 4; ++rr) {
        const int b = b0 + wrow + tr * 16 + rowq + rr;
        const int m = m0 + wcol + tc * 16 + colb;
        p1[obase + (((size_t)(b * F_SZ + f)) << 8) + m] = acc[tr][tc][rr];
      }
}

// recombine 24 slices (3 planes x 8 splits, base 255) -> 3 radix-256 simx digits
__global__ __launch_bounds__(256) void k_digits1(const int* __restrict__ p1, i8* __restrict__ simx) {
  const int idx = blockIdx.x * 256 + threadIdx.x;
  long long g[3];
  #pragma unroll
  for (int p = 0; p < 3; ++p) {
    long long gg = 0;
    #pragma unroll
    for (int s = 0; s < 8; ++s) gg += (long long)p1[(size_t)(p * 8 + s) * NBFM + idx];
    g[p] = gg;
  }
  const long long sim = g[0] + 255LL * g[1] + 65025LL * g[2];
  int x = (int)sim;
  const int r1 = (x + 128) >> 8;
  const int d0 = x - (r1 << 8);
  const int r2 = (r1 + 128) >> 8;
  const int d1 = r1 - (r2 << 8);
  const size_t bf = (size_t)(idx >> 8);
  const int m = idx & 255;
  simx[bf * 768 + m] = (i8)d0;
  simx[bf * 768 + 256 + m] = (i8)d1;
  simx[bf * 768 + 512 + m] = (i8)r2;
}

// ---------------- iteration-1 stage B (NP=3, FIRST) + cbtF write-back ----------------
// grid 1024 = f(4) x ct(256: 4 btiles x 64 dtiles)

__global__ __launch_bounds__(256) void gb_first(
    const i8* __restrict__ simx, const i8* __restrict__ cbt,
    u64* __restrict__ esb, u64* __restrict__ ezb,
    const int* __restrict__ S32, int* __restrict__ changed,
    u64* __restrict__ cbtF)
{
  __shared__ __align__(16) i8 lB[8 * 8 * 64 * 8];   // 32 KB frag-ordered B tile
  __shared__ int chgf;

  const int bid = blockIdx.x;
  const int f = bid & 3;
  const int ct = bid >> 2;
  const int b0 = (ct >> 6) * 64;
  const int d0 = (ct & 63) * 128;

  const int t = threadIdx.x;
  if (t == 0) chgf = 0;
  const int lane = t & 63;
  const int wv = t >> 6;
  const int wrow = (wv >> 1) * 32;
  const int wcol = (wv & 1) * 64;

  {
    const int c = t & 15;
    const int dr0 = t >> 4;
    const int ks = c >> 1;
    const int q0 = (c & 1) * 2;
    #pragma unroll
    for (int i = 0; i < 8; ++i) {
      const int dr = dr0 + i * 16;
      union { c16 v; u64 u[2]; } x;
      x.v = *(const c16*)(cbt + ((size_t)(f * D_SZ + d0 + dr)) * M_SZ + c * 16);
      const int tile = dr >> 4;
      const int col = dr & 15;
      *(u64*)&lB[((((ks * 8 + tile) * 4 + q0) * 16 + col)) * 8] = x.u[0];
      *(u64*)&lB[((((ks * 8 + tile) * 4 + q0 + 1) * 16 + col)) * 8] = x.u[1];
    }
  }
  __syncthreads();

  // one-time: publish frag-ordered tile to global for the persistent loop
  if (bid < 256) {    // exactly the b0==0 blocks: all (f, dtile) combos
    u64* dst = cbtF + ((size_t)(f * 64 + (ct & 63))) * 4096;
    const u64* srcL = (const u64*)lB;
    #pragma unroll
    for (int j = 0; j < 16; ++j) dst[t + j * 256] = srcL[t + j * 256];
  }

  v4i acc[3][2][4];
  #pragma unroll
  for (int pp = 0; pp < 3; ++pp)
    #pragma unroll
    for (int tr = 0; tr < 2; ++tr)
      #pragma unroll
      for (int tc = 0; tc < 4; ++tc) acc[pp][tr][tc] = 0;

  const int rsel = lane & 15;
  const int kq = (lane >> 4) * 8;
  const int tb = wcol >> 4;

  #pragma unroll
  for (int ks = 0; ks < 8; ++ks) {
    long bfv[4];
    #pragma unroll
    for (int tc = 0; tc < 4; ++tc)
      bfv[tc] = *(const long*)&lB[((ks * 8 + tb + tc) * 64 + lane) * 8];
    #pragma unroll
    for (int pp = 0; pp < 3; ++pp) {
      long af[2];
      #pragma unroll
      for (int tr = 0; tr < 2; ++tr) {
        const int row = b0 + wrow + tr * 16 + rsel;
        af[tr] = *(const long*)(simx + ((size_t)(row * 4 + f)) * 768 + pp * 256 + ks * 32 + kq);
      }
      #pragma unroll
      for (int tr = 0; tr < 2; ++tr)
        #pragma unroll
        for (int tc = 0; tc < 4; ++tc)
          acc[pp][tr][tc] = __builtin_amdgcn_mfma_i32_16x16x32_i8(af[tr], bfv[tc], acc[pp][tr][tc], 0, 0, 0);
    }
  }

  bool chl = false;
  const int colb = lane & 15;
  #pragma unroll
  for (int tr = 0; tr < 2; ++tr) {
    u64 bs[4][4], bz[4][4];
    #pragma unroll
    for (int rr = 0; rr < 4; ++rr)
      #pragma unroll
      for (int tc = 0; tc < 4; ++tc) {
        int o = acc[0][tr][tc][rr] + acc[1][tr][tc][rr] * 256 + acc[2][tr][tc][rr] * 65536;
        bs[rr][tc] = __ballot(o < 0);
        bz[rr][tc] = __ballot(o == 0);
        const int sg = (o > 0) - (o < 0);
        const int d = d0 + wcol + tc * 16 + colb;
        chl |= (sg != S32[f * D_SZ + d]);
      }
    u64 ws = 0, wz = 0;
    #pragma unroll
    for (int rl = 0; rl < 16; ++rl) {
      const int g = rl >> 2, rr = rl & 3;
      u64 vs = 0, vz = 0;
      #pragma unroll
      for (int tc = 0; tc < 4; ++tc) {
        vs |= ((bs[rr][tc] >> (g * 16)) & 0xFFFFull) << (tc * 16);
        vz |= ((bz[rr][tc] >> (g * 16)) & 0xFFFFull) << (tc * 16);
      }
      if (lane == rl) { ws = vs; wz = vz; }
    }
    if (lane < 16) {
      const int row = b0 + wrow + tr * 16 + lane;
      const size_t wi = ((size_t)(row * 4 + f)) * 128 + ((d0 + wcol) >> 6);
      esb[wi] = ws;
      ezb[wi] = wz;
    }
  }
  if (chl) atomicOr(&chgf, 1);
  __syncthreads();
  if (t == 0 && chgf) atomicOr(&changed[1], 1);
}

// ---------------- persistent kernel: iterations 2..10 + final argmax ----------------
// grid 256 x 1024. Block bid owns (f_own = bid>>6, dt_own = bid&63): its 32 KB stage-B
// weight tile lives in LDS for the whole kernel. Steady state is L2-resident.

__global__ __launch_bounds__(1024) void k_persist(
    u64* __restrict__ esb, u64* __restrict__ ezb,
    const u64* __restrict__ inb, const u64* __restrict__ cbbT,
    const u64* __restrict__ cbtF, i8* __restrict__ simx,
    int* __restrict__ chg, int* __restrict__ bar, int* __restrict__ out)
{
  __shared__ __align__(16) char lS[32768 + 25600];  // [0,32K): B-frag tile; then 2x12800 unit scratch
  __shared__ int chgf;

  const int bid = blockIdx.x;
  const int t = threadIdx.x;
  const int lane = t & 63;
  const int f_own = bid >> 6;
  const int dt_own = bid & 63;

  // ---- one-time: preload owned B-frag tile into LDS (coalesced, conflict-free) ----
  {
    const u64* srcG = cbtF + ((size_t)(f_own * 64 + dt_own)) * 4096;
    u64* dstL = (u64*)lS;
    #pragma unroll
    for (int j = 0; j < 4; ++j) dstL[t + j * 1024] = srcG[t + j * 1024];
  }
  __syncthreads();

  for (int it = 2; it <= NITER; ++it) {
    const bool active =
        __hip_atomic_load(&chg[it - 1], __ATOMIC_RELAXED, __HIP_MEMORY_SCOPE_AGENT) != 0;
    if (t == 0) chgf = 0;

    // ---- phase A: bitwise sims (512 units; 2 per block, 512 threads each) ----
    if (active) {
      const int sub = t >> 9;             // 0..1
      const int tl = t & 511;
      u64* AL = (u64*)(lS + 32768 + sub * 12800);            // AL[j*128 + w]
      int* C0 = (int*)(lS + 32768 + sub * 12800 + 4096);     // [2]
      int* P  = (int*)(lS + 32768 + sub * 12800 + 4224);     // [(h*2+r)*256 + m]
      const int unit = bid * 2 + sub;
      const int f = unit & 3;
      const int b0 = (unit >> 2) * 2;
      if (tl < 2) C0[tl] = 0;
      __syncthreads();
      if (tl < 256) {
        const int r = tl >> 7, w = tl & 127;
        const int b = b0 + r;
        int ffs[3]; int c = 0;
        for (int ff = 0; ff < 4; ++ff) if (ff != f) ffs[c++] = ff;
        const size_t base = (size_t)b * 512;
        const u64 s = inb[(size_t)b * 128 + w]
          ^ esb[base + ffs[0] * 128 + w] ^ esb[base + ffs[1] * 128 + w] ^ esb[base + ffs[2] * 128 + w];
        const u64 z = ~(ezb[base + ffs[0] * 128 + w] | ezb[base + ffs[1] * 128 + w] | ezb[base + ffs[2] * 128 + w]);
        AL[(r * 2 + 0) * 128 + w] = s;
        AL[(r * 2 + 1) * 128 + w] = z;
        int pcv = (int)__popcll(z);
        #pragma unroll
        for (int off = 32; off >= 1; off >>= 1) pcv += __shfl_down(pcv, off);
        if (lane == 0) atomicAdd(&C0[r], pcv);
      }
      __syncthreads();
      {
        const int h = tl >> 8;            // w-half
        const int m = tl & 255;
        int pa0 = 0, pa1 = 0;
        const u64* pc = cbbT + (size_t)f * 32768 + m;
        const int w0 = h * 64;
        #pragma unroll 4
        for (int w = w0; w < w0 + 64; ++w) {
          const u64 cbw = pc[w * 256];
          pa0 += (int)__popcll((AL[0 * 128 + w] ^ cbw) & AL[1 * 128 + w]);
          pa1 += (int)__popcll((AL[2 * 128 + w] ^ cbw) & AL[3 * 128 + w]);
        }
        P[(h * 2 + 0) * 256 + m] = pa0;
        P[(h * 2 + 1) * 256 + m] = pa1;
      }
      __syncthreads();
      if (tl < 256) {
        const int m = tl;
        const int a0 = P[0 * 256 + m] + P[2 * 256 + m];
        const int a1 = P[1 * 256 + m] + P[3 * 256 + m];
        const int sim0 = C0[0] - 2 * a0;
        const int sim1 = C0[1] - 2 * a1;
        int d1 = (sim0 + 128) >> 8; int d0v = sim0 - (d1 << 8);
        const size_t bf0 = ((size_t)b0 * 4 + f) * 768;
        simx[bf0 + m] = (i8)d0v; simx[bf0 + 256 + m] = (i8)d1;
        d1 = (sim1 + 128) >> 8; d0v = sim1 - (d1 << 8);
        const size_t bf1 = ((size_t)(b0 + 1) * 4 + f) * 768;
        simx[bf1 + m] = (i8)d0v; simx[bf1 + 256 + m] = (i8)d1;
      }
    }
    gridbar(bar, t);

    // ---- phase B: MFMA stage-B from LDS weights (4 btiles; 4 subs of 256 thr) ----
    if (active) {
      const int sub = t >> 8;             // btile 0..3
      const int tl = t & 255;
      const int f = f_own;
      const int b0 = sub * 64;
      const int wv = tl >> 6;
      const int wrow = (wv >> 1) * 32;
      const int wcol = (wv & 1) * 64;

      v4i acc[2][2][4];
      #pragma unroll
      for (int pp = 0; pp < 2; ++pp)
        #pragma unroll
        for (int tr = 0; tr < 2; ++tr)
          #pragma unroll
          for (int tc = 0; tc < 4; ++tc) acc[pp][tr][tc] = 0;

      const int rsel = lane & 15;
      const int kq = (lane >> 4) * 8;
      const int tb = wcol >> 4;

      #pragma unroll
      for (int ks = 0; ks < 8; ++ks) {
        long bfv[4];
        #pragma unroll
        for (int tc = 0; tc < 4; ++tc)
          bfv[tc] = *(const long*)&lS[((ks * 8 + tb + tc) * 64 + lane) * 8];
        #pragma unroll
        for (int pp = 0; pp < 2; ++pp) {
          long af[2];
          #pragma unroll
          for (int tr = 0; tr < 2; ++tr) {
            const int row = b0 + wrow + tr * 16 + rsel;
            af[tr] = *(const long*)(simx + ((size_t)(row * 4 + f)) * 768 + pp * 256 + ks * 32 + kq);
          }
          #pragma unroll
          for (int tr = 0; tr < 2; ++tr)
            #pragma unroll
            for (int tc = 0; tc < 4; ++tc)
              acc[pp][tr][tc] = __builtin_amdgcn_mfma_i32_16x16x32_i8(af[tr], bfv[tc], acc[pp][tr][tc], 0, 0, 0);
        }
      }

      bool chl = false;
      #pragma unroll
      for (int tr = 0; tr < 2; ++tr) {
        u64 bs[4][4], bz[4][4];
        #pragma unroll
        for (int rr = 0; rr < 4; ++rr)
          #pragma unroll
          for (int tc = 0; tc < 4; ++tc) {
            const int o = acc[0][tr][tc][rr] + acc[1][tr][tc][rr] * 256;
            bs[rr][tc] = __ballot(o < 0);
            bz[rr][tc] = __ballot(o == 0);
          }
        u64 ws = 0, wz = 0;
        #pragma unroll
        for (int rl = 0; rl < 16; ++rl) {
          const int g = rl >> 2, rr = rl & 3;
          u64 vs = 0, vz = 0;
          #pragma unroll
          for (int tc = 0; tc < 4; ++tc) {
            vs |= ((bs[rr][tc] >> (g * 16)) & 0xFFFFull) << (tc * 16);
            vz |= ((bz[rr][tc] >> (g * 16)) & 0xFFFFull) << (tc * 16);
          }
          if (lane == rl) { ws = vs; wz = vz; }
        }
        if (lane < 16) {
          const int row = b0 + wrow + tr * 16 + lane;
          const size_t wi = ((size_t)(row * 4 + f)) * 128 + (dt_own << 1) + (wcol >> 6);
          chl |= (ws != esb[wi]) | (wz != ezb[wi]);
          esb[wi] = ws;
          ezb[wi] = wz;
        }
      }
      if (chl) atomicOr(&chgf, 1);
      __syncthreads();
      if (t == 0 && chgf) atomicOr(&chg[it], 1);
    }
    gridbar(bar, t);
  }

  // ---- final: sim + argmax + k (512 units; 2 per block) ----
  {
    const int sub = t >> 9;
    const int tl = t & 511;
    u64* AL = (u64*)(lS + 32768 + sub * 12800);
    int* C0 = (int*)(lS + 32768 + sub * 12800 + 4096);
    int* P  = (int*)(lS + 32768 + sub * 12800 + 4224);
    long long* red0 = (long long*)(lS + 32768 + sub * 12800 + 8320);
    long long* red1 = (long long*)(lS + 32768 + sub * 12800 + 10368);
    const int unit = bid * 2 + sub;
    const int f = unit & 3;
    const int b0 = (unit >> 2) * 2;
    if (tl < 2) C0[tl] = 0;
    __syncthreads();
    if (tl < 256) {
      const int r = tl >> 7, w = tl & 127;
      const int b = b0 + r;
      const size_t a = ((size_t)b * 4 + f) * 128 + w;
      const u64 s = esb[a];
      const u64 z = ~ezb[a];
      AL[(r * 2 + 0) * 128 + w] = s;
      AL[(r * 2 + 1) * 128 + w] = z;
      int pcv = (int)__popcll(z);
      #pragma unroll
      for (int off = 32; off >= 1; off >>= 1) pcv += __shfl_down(pcv, off);
      if (lane == 0) atomicAdd(&C0[r], pcv);
    }
    __syncthreads();
    {
      const int h = tl >> 8;
      const int m = tl & 255;
      int pa0 = 0, pa1 = 0;
      const u64* pc = cbbT + (size_t)f * 32768 + m;
      const int w0 = h * 64;
      #pragma unroll 4
      for (int w = w0; w < w0 + 64; ++w) {
        const u64 cbw = pc[w * 256];
        pa0 += (int)__popcll((AL[0 * 128 + w] ^ cbw) & AL[1 * 128 + w]);
        pa1 += (int)__popcll((AL[2 * 128 + w] ^ cbw) & AL[3 * 128 + w]);
      }
      P[(h * 2 + 0) * 256 + m] = pa0;
      P[(h * 2 + 1) * 256 + m] = pa1;
    }
    __syncthreads();
    if (tl < 256) {
      const int m = tl;
      const int a0 = P[0 * 256 + m] + P[2 * 256 + m];
      const int a1 = P[1 * 256 + m] + P[3 * 256 + m];
      const int sim0 = C0[0] - 2 * a0;
      const int sim1 = C0[1] - 2 * a1;
      red0[m] = ((long long)sim0 << 32) | (long long)(unsigned)(255 - m);
      red1[m] = ((long long)sim1 << 32) | (long long)(unsigned)(255 - m);
    }
    __syncthreads();
    for (int s2 = 128; s2 > 0; s2 >>= 1) {
      if (tl < s2) {
        if (red0[tl + s2] > red0[tl]) red0[tl] = red0[tl + s2];
        if (red1[tl + s2] > red1[tl]) red1[tl] = red1[tl + s2];
      }
      __syncthreads();
    }
    if (tl == 0) {
      out[b0 * 4 + f] = 255 - (int)(red0[0] & 0xFFFF);
      out[(b0 + 1) * 4 + f] = 255 - (int)(red1[0] & 0xFFFF);
      if (unit == 0) {
        int k = NITER;
        for (int i = 1; i <= NITER; ++i)
          if (__hip_atomic_load(&chg[i], __ATOMIC_RELAXED, __HIP_MEMORY_SCOPE_AGENT) == 0) { k = i; break; }
        out[B_SZ * F_SZ] = k;
      }
    }
  }
}

// ---------------- host ----------------

extern "C" void kernel_launch(void* const* d_in, const int* in_sizes, int n_in,
                              void* d_out, int out_size, void* d_ws, size_t ws_size,
                              hipStream_t stream) {
  const float* f_in = (const float*)d_in[0];   // [B][D]
  const float* f_cb = (const float*)d_in[1];   // [F][M][D]
  int* out = (int*)d_out;
  char* ws = (char*)d_ws;

  i8*  cb8  = (i8*)(ws + OFF_CB);
  i8*  cbt8 = (i8*)(ws + OFF_CBT);
  i8*  in8  = (i8*)(ws + OFF_IN8);
  u64* cbbT = (u64*)(ws + OFF_CBBT);
  u64* inb  = (u64*)(ws + OFF_INB);
  u64* esb  = (u64*)(ws + OFF_ESB);
  u64* ezb  = (u64*)(ws + OFF_EZB);
  i8*  simx = (i8*)(ws + OFF_SIMX);
  int* p1   = (int*)(ws + OFF_P1);
  u64* cbtF = (u64*)(ws + OFF_CBTF);   // aliases p1 (p1 dead after k_digits1)
  int* S32  = (int*)(ws + OFF_S32);
  int* chg  = (int*)(ws + OFF_CHG);
  int* bar  = (int*)(ws + OFF_BAR);
  i8*  pdig = (i8*)(ws + OFF_PDIG);

  // zero S32 (atomic target) + chg flags + barrier state in one memset
  hipMemsetAsync(ws + OFF_S32, 0, 131072 + 128, stream);
  k_prep_cb<<<dim3(8192), dim3(256), 0, stream>>>(f_cb, cb8, cbt8, cbbT, S32);
  k_prep_in<<<dim3(2048), dim3(256), 0, stream>>>(f_in, in8, inb);
  k_P<<<dim3(32), dim3(256), 0, stream>>>(S32, pdig);

  // iteration 1 (big-integer est0 via P/8 digit planes, MFMA)
  ga2_kernel<<<dim3(768), dim3(256), 0, stream>>>(in8, cb8, pdig, p1);
  k_digits1<<<dim3(1024), dim3(256), 0, stream>>>(p1, simx);
  gb_first<<<dim3(1024), dim3(256), 0, stream>>>(simx, cbt8, esb, ezb, S32, chg, cbtF);

  // iterations 2..10 + final argmax in one persistent kernel (256 blocks x 1024 thr)
  k_persist<<<dim3(256), dim3(1024), 0, stream>>>(esb, ezb, inb, cbbT, cbtF, simx, chg, bar, out);
}

// Round 8
// 773.224 us; speedup vs baseline: 1.8959x; 1.7075x over previous
//
#include <hip/hip_runtime.h>

#define B_SZ 256
#define F_SZ 4
#define M_SZ 256
#define D_SZ 8192
#define NITER 10

typedef signed char i8;
typedef unsigned long long u64;
typedef signed char c16 __attribute__((ext_vector_type(16)));
typedef int v4i __attribute__((ext_vector_type(4)));

#define NBFM (B_SZ * F_SZ * M_SZ)   // 262144

// ---- workspace layout (bytes) ----
#define OFF_CB    ((size_t)0)          // i8  [F][M][D]      8 MB
#define OFF_CBT   ((size_t)8  << 20)   // i8  [F][D][M]      8 MB
#define OFF_IN8   ((size_t)16 << 20)   // i8  [B][D]         2 MB
#define OFF_CBBT  ((size_t)18 << 20)   // u64 [F][128][M]    1 MB
#define OFF_INB   ((size_t)19 << 20)   // u64 [B][128]       256 KB
#define OFF_ESB   ((size_t)20 << 20)   // u64 [B][F][128]    1 MB  (sign bits, in-place)
#define OFF_EZB   ((size_t)21 << 20)   // u64 [B][F][128]    1 MB  (zero bits, in-place)
#define OFF_SIMX  ((size_t)22 << 20)   // i8  [B*F][768]     768 KB (digit planes, u64-granular)
#define OFF_P1    ((size_t)23 << 20)   // i32 [24][B*F*M]    24 MB  (iter1 partials)
#define OFF_CBTF  OFF_P1               // u64 [F][64][4096]  8 MB   (aliases p1)
#define OFF_S32   ((size_t)47 << 20)   // i32 [F][D]         128 KB (zeroed)
#define OFF_CHG   (OFF_S32 + (size_t)131072)            // int[16] (zeroed)
#define OFF_BAR   (OFF_CHG + (size_t)64)                // int[16] (zeroed)
#define OFF_PDIG  (OFF_BAR + (size_t)64)                // i8 [3][F][D] 96 KB

__device__ __forceinline__ u64 msk8(u64 x) {
  return (((x >> 7) & 0x0101010101010101ull) * 0x0102040810204080ull) >> 56;
}

// agent-scope relaxed (coherent, L2-bypassing) accessors — no fences attached
__device__ __forceinline__ u64 aload(const u64* p) {
  return __hip_atomic_load(p, __ATOMIC_RELAXED, __HIP_MEMORY_SCOPE_AGENT);
}
__device__ __forceinline__ void astore(u64* p, u64 v) {
  __hip_atomic_store(p, v, __ATOMIC_RELAXED, __HIP_MEMORY_SCOPE_AGENT);
}

// fence-free device-wide generation barrier for a 256-block persistent kernel.
// All inter-block data moves via coherent relaxed atomics, so no buffer_inv /
// buffer_wbl2 is ever required — just drain outstanding stores (s_waitcnt 0).
__device__ __forceinline__ void gridbar(int* bar, int t) {
  __syncthreads();
  if (t == 0) {
    __atomic_signal_fence(__ATOMIC_SEQ_CST);
    __builtin_amdgcn_s_waitcnt(0);      // coherent stores retired at coherence point
    __atomic_signal_fence(__ATOMIC_SEQ_CST);
    const int g = __hip_atomic_load(&bar[1], __ATOMIC_RELAXED, __HIP_MEMORY_SCOPE_AGENT);
    const int v = __hip_atomic_fetch_add(&bar[0], 1, __ATOMIC_RELAXED, __HIP_MEMORY_SCOPE_AGENT);
    if (v == 255) {
      __hip_atomic_store(&bar[0], 0, __ATOMIC_RELAXED, __HIP_MEMORY_SCOPE_AGENT);
      __atomic_signal_fence(__ATOMIC_SEQ_CST);
      __builtin_amdgcn_s_waitcnt(0);    // reset globally visible before release bump
      __atomic_signal_fence(__ATOMIC_SEQ_CST);
      __hip_atomic_fetch_add(&bar[1], 1, __ATOMIC_RELAXED, __HIP_MEMORY_SCOPE_AGENT);
    } else {
      while (__hip_atomic_load(&bar[1], __ATOMIC_RELAXED, __HIP_MEMORY_SCOPE_AGENT) == g)
        __builtin_amdgcn_s_sleep(8);    // relaxed poll: NO buffer_inv per poll
    }
  }
  __syncthreads();
}

// ---------------- fused setup ----------------
// grid 8192 = f(4) x mt(16) x dt(128); tile = 16 m x 64 d

__global__ __launch_bounds__(256) void k_prep_cb(const float* __restrict__ src,
                                                 i8* __restrict__ cb, i8* __restrict__ cbt,
                                                 u64* __restrict__ cbbT, int* __restrict__ S32) {
  __shared__ __align__(16) i8 tile[16][64];
  const int bid = blockIdx.x;
  const int f = bid >> 11;
  const int mt = (bid >> 7) & 15;
  const int dt = bid & 127;
  const int m0 = mt * 16, d0 = dt * 64;
  const int t = threadIdx.x;
  const int mi = t >> 4, c = t & 15;
  const float4 v = *(const float4*)(src + ((size_t)(f * M_SZ + m0 + mi)) * D_SZ + d0 + c * 4);
  char4 cc;
  cc.x = v.x > 0.f ? 1 : -1;
  cc.y = v.y > 0.f ? 1 : -1;
  cc.z = v.z > 0.f ? 1 : -1;
  cc.w = v.w > 0.f ? 1 : -1;
  *(char4*)(cb + ((size_t)(f * M_SZ + m0 + mi)) * D_SZ + d0 + c * 4) = cc;
  *(char4*)&tile[mi][c * 4] = cc;
  __syncthreads();
  if (t < 64) {
    const int dd = t;
    c16 o;
    int ssum = 0;
    #pragma unroll
    for (int mm = 0; mm < 16; ++mm) { const i8 val = tile[mm][dd]; o[mm] = val; ssum += val; }
    *(c16*)(cbt + ((size_t)(f * D_SZ + d0 + dd)) * M_SZ + m0) = o;
    atomicAdd(&S32[f * D_SZ + d0 + dd], ssum);
  } else if (t < 80) {
    const int m = t - 64;
    const u64* row = (const u64*)&tile[m][0];
    u64 w = 0;
    #pragma unroll
    for (int j = 0; j < 8; ++j) w |= msk8(row[j]) << (8 * j);
    cbbT[((size_t)(f * 128 + dt)) * 256 + (m0 + m)] = w;
  }
}

// grid 2048 = bt(16) x dt(128); tile = 16 b x 64 d
__global__ __launch_bounds__(256) void k_prep_in(const float* __restrict__ src,
                                                 i8* __restrict__ dst, u64* __restrict__ inb) {
  __shared__ __align__(16) i8 tile[16][64];
  const int bid = blockIdx.x;
  const int bt = bid >> 7;
  const int dt = bid & 127;
  const int b0 = bt * 16, d0 = dt * 64;
  const int t = threadIdx.x;
  const int mi = t >> 4, c = t & 15;
  const float4 v = *(const float4*)(src + ((size_t)(b0 + mi)) * D_SZ + d0 + c * 4);
  char4 cc;
  cc.x = v.x > 0.f ? 1 : -1;
  cc.y = v.y > 0.f ? 1 : -1;
  cc.z = v.z > 0.f ? 1 : -1;
  cc.w = v.w > 0.f ? 1 : -1;
  *(char4*)(dst + ((size_t)(b0 + mi)) * D_SZ + d0 + c * 4) = cc;
  *(char4*)&tile[mi][c * 4] = cc;
  __syncthreads();
  if (t < 16) {
    const u64* row = (const u64*)&tile[t][0];
    u64 w = 0;
    #pragma unroll
    for (int j = 0; j < 8; ++j) w |= msk8(row[j]) << (8 * j);
    inb[(size_t)(b0 + t) * 128 + dt] = w;
  }
}

// P' = P/8 (exact: each S is even), 3 radix-255 signed digits in [-127,127]
__global__ __launch_bounds__(256) void k_P(const int* __restrict__ S, i8* __restrict__ pdig) {
  const int d = blockIdx.x * 256 + threadIdx.x;     // 8192
  const int s0 = S[d], s1 = S[D_SZ + d], s2 = S[2 * D_SZ + d], s3 = S[3 * D_SZ + d];
  int P[4];
  P[0] = s1 * s2 * s3;
  P[1] = s0 * s2 * s3;
  P[2] = s0 * s1 * s3;
  P[3] = s0 * s1 * s2;
  for (int f = 0; f < 4; ++f) {
    int x = P[f] >> 3;                 // exact (divisible by 8)
    #pragma unroll
    for (int p = 0; p < 2; ++p) {
      const int y = x + 127;
      const int q = (y >= 0) ? (y / 255) : -((-y + 254) / 255);   // floor-style
      const int dg = x - q * 255;      // in [-127,127]
      pdig[((size_t)(p * F_SZ + f)) * D_SZ + d] = (i8)dg;
      x = q;
    }
    pdig[((size_t)(2 * F_SZ + f)) * D_SZ + d] = (i8)x;   // |x| small
  }
}

// ---------------- iteration-1 stage A (MFMA, 3 digit planes of P/8) ----------------
// grid 768: bid = s(8) + 8*( p(3) + 3*( f(4) + 4*ct(8) ) )

__global__ __launch_bounds__(256) void ga2_kernel(
    const i8* __restrict__ in8, const i8* __restrict__ cb,
    const i8* __restrict__ pdig, int* __restrict__ p1)
{
  __shared__ __align__(16) i8 lA[64 * 48];
  __shared__ __align__(16) i8 lB[128 * 48];

  const int bid = blockIdx.x;
  const int s = bid & 7;
  const int r = bid >> 3;
  const int p = r % 3;
  const int q = r / 3;
  const int f = q & 3;
  const int ct = q >> 2;
  const int b0 = (ct >> 1) * 64;
  const int m0 = (ct & 1) * 128;
  const int ksteps = 32;
  const int kbase = s << 10;

  const int t = threadIdx.x;
  const int lane = t & 63;
  const int wv = t >> 6;
  const int wrow = (wv >> 1) * 32;
  const int wcol = (wv & 1) * 64;

  const int arow = t >> 1;
  const int aoff = (t & 1) * 16;
  const i8* pB  = cb   + ((size_t)(f * M_SZ + m0 + arow)) * D_SZ + aoff;
  const i8* pDg = pdig + ((size_t)(p * F_SZ + f)) * D_SZ + aoff;
  const i8* pIn = in8  + (size_t)(b0 + arow) * D_SZ + aoff;

  v4i acc[2][4];
  #pragma unroll
  for (int tr = 0; tr < 2; ++tr)
    #pragma unroll
    for (int tc = 0; tc < 4; ++tc) acc[tr][tc] = 0;

  c16 va = 0, vb = 0;
  {
    const int kk = kbase;
    vb = (*(const c16*)(pB + kk)) * (*(const c16*)(pDg + kk));
    if (t < 128) va = *(const c16*)(pIn + kk);
  }

  for (int j = 0; j < ksteps; ++j) {
    c16 sa = va, sb = vb;
    if (j + 1 < ksteps) {
      const int kk = kbase + (j + 1) * 32;
      vb = (*(const c16*)(pB + kk)) * (*(const c16*)(pDg + kk));
      if (t < 128) va = *(const c16*)(pIn + kk);
    }
    __syncthreads();
    if (t < 128) *(c16*)&lA[arow * 48 + aoff] = sa;
    *(c16*)&lB[arow * 48 + aoff] = sb;
    __syncthreads();

    const int rsel = lane & 15;
    const int kq = (lane >> 4) * 8;
    long af[2], bf[4];
    #pragma unroll
    for (int tr = 0; tr < 2; ++tr) af[tr] = *(const long*)&lA[(wrow + tr * 16 + rsel) * 48 + kq];
    #pragma unroll
    for (int tc = 0; tc < 4; ++tc) bf[tc] = *(const long*)&lB[(wcol + tc * 16 + rsel) * 48 + kq];
    #pragma unroll
    for (int tr = 0; tr < 2; ++tr)
      #pragma unroll
      for (int tc = 0; tc < 4; ++tc)
        acc[tr][tc] = __builtin_amdgcn_mfma_i32_16x16x32_i8(af[tr], bf[tc], acc[tr][tc], 0, 0, 0);
  }

  const int colb = lane & 15;
  const int rowq = (lane >> 4) * 4;
  const size_t obase = (size_t)(p * 8 + s) * NBFM;
  #pragma unroll
  for (int tr = 0; tr < 2; ++tr)
    #pragma unroll
    for (int tc = 0; tc < 4; ++tc)
      #pragma unroll
      for (int rr = 0; rr < 4; ++rr) {
        const int b = b0 + wrow + tr * 16 + rowq + rr;
        const int m = m0 + wcol + tc * 16 + colb;
        p1[obase + (((size_t)(b * F_SZ + f)) << 8) + m] = acc[tr][tc][rr];
      }
}

// recombine 24 slices (3 planes x 8 splits, base 255) -> 3 radix-256 simx digits
__global__ __launch_bounds__(256) void k_digits1(const int* __restrict__ p1, i8* __restrict__ simx) {
  const int idx = blockIdx.x * 256 + threadIdx.x;
  long long g[3];
  #pragma unroll
  for (int p = 0; p < 3; ++p) {
    long long gg = 0;
    #pragma unroll
    for (int s = 0; s < 8; ++s) gg += (long long)p1[(size_t)(p * 8 + s) * NBFM + idx];
    g[p] = gg;
  }
  const long long sim = g[0] + 255LL * g[1] + 65025LL * g[2];
  int x = (int)sim;
  const int r1 = (x + 128) >> 8;
  const int d0 = x - (r1 << 8);
  const int r2 = (r1 + 128) >> 8;
  const int d1 = r1 - (r2 << 8);
  const size_t bf = (size_t)(idx >> 8);
  const int m = idx & 255;
  simx[bf * 768 + m] = (i8)d0;
  simx[bf * 768 + 256 + m] = (i8)d1;
  simx[bf * 768 + 512 + m] = (i8)r2;
}

// ---------------- iteration-1 stage B (NP=3, FIRST) + cbtF write-back ----------------
// grid 1024 = f(4) x ct(256: 4 btiles x 64 dtiles)

__global__ __launch_bounds__(256) void gb_first(
    const i8* __restrict__ simx, const i8* __restrict__ cbt,
    u64* __restrict__ esb, u64* __restrict__ ezb,
    const int* __restrict__ S32, int* __restrict__ changed,
    u64* __restrict__ cbtF)
{
  __shared__ __align__(16) i8 lB[8 * 8 * 64 * 8];   // 32 KB frag-ordered B tile
  __shared__ int chgf;

  const int bid = blockIdx.x;
  const int f = bid & 3;
  const int ct = bid >> 2;
  const int b0 = (ct >> 6) * 64;
  const int d0 = (ct & 63) * 128;

  const int t = threadIdx.x;
  if (t == 0) chgf = 0;
  const int lane = t & 63;
  const int wv = t >> 6;
  const int wrow = (wv >> 1) * 32;
  const int wcol = (wv & 1) * 64;

  {
    const int c = t & 15;
    const int dr0 = t >> 4;
    const int ks = c >> 1;
    const int q0 = (c & 1) * 2;
    #pragma unroll
    for (int i = 0; i < 8; ++i) {
      const int dr = dr0 + i * 16;
      union { c16 v; u64 u[2]; } x;
      x.v = *(const c16*)(cbt + ((size_t)(f * D_SZ + d0 + dr)) * M_SZ + c * 16);
      const int tile = dr >> 4;
      const int col = dr & 15;
      *(u64*)&lB[((((ks * 8 + tile) * 4 + q0) * 16 + col)) * 8] = x.u[0];
      *(u64*)&lB[((((ks * 8 + tile) * 4 + q0 + 1) * 16 + col)) * 8] = x.u[1];
    }
  }
  __syncthreads();

  // one-time: publish frag-ordered tile to global for the persistent loop
  if (bid < 256) {    // exactly the b0==0 blocks: all (f, dtile) combos
    u64* dst = cbtF + ((size_t)(f * 64 + (ct & 63))) * 4096;
    const u64* srcL = (const u64*)lB;
    #pragma unroll
    for (int j = 0; j < 16; ++j) dst[t + j * 256] = srcL[t + j * 256];
  }

  v4i acc[3][2][4];
  #pragma unroll
  for (int pp = 0; pp < 3; ++pp)
    #pragma unroll
    for (int tr = 0; tr < 2; ++tr)
      #pragma unroll
      for (int tc = 0; tc < 4; ++tc) acc[pp][tr][tc] = 0;

  const int rsel = lane & 15;
  const int kq = (lane >> 4) * 8;
  const int tb = wcol >> 4;

  #pragma unroll
  for (int ks = 0; ks < 8; ++ks) {
    long bfv[4];
    #pragma unroll
    for (int tc = 0; tc < 4; ++tc)
      bfv[tc] = *(const long*)&lB[((ks * 8 + tb + tc) * 64 + lane) * 8];
    #pragma unroll
    for (int pp = 0; pp < 3; ++pp) {
      long af[2];
      #pragma unroll
      for (int tr = 0; tr < 2; ++tr) {
        const int row = b0 + wrow + tr * 16 + rsel;
        af[tr] = *(const long*)(simx + ((size_t)(row * 4 + f)) * 768 + pp * 256 + ks * 32 + kq);
      }
      #pragma unroll
      for (int tr = 0; tr < 2; ++tr)
        #pragma unroll
        for (int tc = 0; tc < 4; ++tc)
          acc[pp][tr][tc] = __builtin_amdgcn_mfma_i32_16x16x32_i8(af[tr], bfv[tc], acc[pp][tr][tc], 0, 0, 0);
    }
  }

  bool chl = false;
  const int colb = lane & 15;
  #pragma unroll
  for (int tr = 0; tr < 2; ++tr) {
    u64 bs[4][4], bz[4][4];
    #pragma unroll
    for (int rr = 0; rr < 4; ++rr)
      #pragma unroll
      for (int tc = 0; tc < 4; ++tc) {
        int o = acc[0][tr][tc][rr] + acc[1][tr][tc][rr] * 256 + acc[2][tr][tc][rr] * 65536;
        bs[rr][tc] = __ballot(o < 0);
        bz[rr][tc] = __ballot(o == 0);
        const int sg = (o > 0) - (o < 0);
        const int d = d0 + wcol + tc * 16 + colb;
        chl |= (sg != S32[f * D_SZ + d]);
      }
    u64 ws = 0, wz = 0;
    #pragma unroll
    for (int rl = 0; rl < 16; ++rl) {
      const int g = rl >> 2, rr = rl & 3;
      u64 vs = 0, vz = 0;
      #pragma unroll
      for (int tc = 0; tc < 4; ++tc) {
        vs |= ((bs[rr][tc] >> (g * 16)) & 0xFFFFull) << (tc * 16);
        vz |= ((bz[rr][tc] >> (g * 16)) & 0xFFFFull) << (tc * 16);
      }
      if (lane == rl) { ws = vs; wz = vz; }
    }
    if (lane < 16) {
      const int row = b0 + wrow + tr * 16 + lane;
      const size_t wi = ((size_t)(row * 4 + f)) * 128 + ((d0 + wcol) >> 6);
      esb[wi] = ws;
      ezb[wi] = wz;
    }
  }
  if (chl) atomicOr(&chgf, 1);
  __syncthreads();
  if (t == 0 && chgf) atomicOr(&changed[1], 1);
}

// ---------------- persistent kernel: iterations 2..10 + final argmax ----------------
// grid 256 x 1024. Block bid owns (f_own, dt_own); 32 KB weight tile pinned in LDS.
// All cross-block data via agent-relaxed coherent atomics; fence-free barrier.

__global__ __launch_bounds__(1024) void k_persist(
    u64* __restrict__ esb, u64* __restrict__ ezb,
    const u64* __restrict__ inb, const u64* __restrict__ cbbT,
    const u64* __restrict__ cbtF, u64* __restrict__ simx64,
    int* __restrict__ chg, int* __restrict__ bar, int* __restrict__ out)
{
  __shared__ __align__(16) char lS[32768 + 25600];  // [0,32K): B-frag tile; then 2x12800 scratch
  __shared__ int chgf;

  const int bid = blockIdx.x;
  const int t = threadIdx.x;
  const int lane = t & 63;
  const int f_own = bid >> 6;
  const int dt_own = bid & 63;

  // ---- one-time: preload owned B-frag tile into LDS ----
  {
    const u64* srcG = cbtF + ((size_t)(f_own * 64 + dt_own)) * 4096;
    u64* dstL = (u64*)lS;
    #pragma unroll
    for (int j = 0; j < 4; ++j) dstL[t + j * 1024] = srcG[t + j * 1024];
  }
  __syncthreads();

  for (int it = 2; it <= NITER; ++it) {
    const bool active =
        __hip_atomic_load(&chg[it - 1], __ATOMIC_RELAXED, __HIP_MEMORY_SCOPE_AGENT) != 0;
    if (t == 0) chgf = 0;

    // ---- phase A: bitwise sims (512 units; 2 per block, 512 threads each) ----
    if (active) {
      const int sub = t >> 9;             // 0..1
      const int tl = t & 511;
      u64* AL  = (u64*)(lS + 32768 + sub * 12800);            // AL[j*128 + w]
      int* C0  = (int*)(lS + 32768 + sub * 12800 + 4096);     // [2]
      int* P   = (int*)(lS + 32768 + sub * 12800 + 4224);     // [(h*2+r)*256 + m]
      i8*  stg = (i8*)(lS + 32768 + sub * 12800 + 8320);      // [2][768] digit staging
      const int unit = bid * 2 + sub;
      const int f = unit & 3;
      const int b0 = (unit >> 2) * 2;
      if (tl < 2) C0[tl] = 0;
      __syncthreads();
      if (tl < 256) {
        const int r = tl >> 7, w = tl & 127;
        const int b = b0 + r;
        int ffs[3]; int c = 0;
        for (int ff = 0; ff < 4; ++ff) if (ff != f) ffs[c++] = ff;
        const size_t base = (size_t)b * 512;
        const u64 s = inb[(size_t)b * 128 + w]
          ^ aload(esb + base + ffs[0] * 128 + w) ^ aload(esb + base + ffs[1] * 128 + w)
          ^ aload(esb + base + ffs[2] * 128 + w);
        const u64 z = ~(aload(ezb + base + ffs[0] * 128 + w) | aload(ezb + base + ffs[1] * 128 + w)
                      | aload(ezb + base + ffs[2] * 128 + w));
        AL[(r * 2 + 0) * 128 + w] = s;
        AL[(r * 2 + 1) * 128 + w] = z;
        int pcv = (int)__popcll(z);
        #pragma unroll
        for (int off = 32; off >= 1; off >>= 1) pcv += __shfl_down(pcv, off);
        if (lane == 0) atomicAdd(&C0[r], pcv);
      }
      __syncthreads();
      {
        const int h = tl >> 8;            // w-half
        const int m = tl & 255;
        int pa0 = 0, pa1 = 0;
        const u64* pc = cbbT + (size_t)f * 32768 + m;
        const int w0 = h * 64;
        #pragma unroll 4
        for (int w = w0; w < w0 + 64; ++w) {
          const u64 cbw = pc[w * 256];
          pa0 += (int)__popcll((AL[0 * 128 + w] ^ cbw) & AL[1 * 128 + w]);
          pa1 += (int)__popcll((AL[2 * 128 + w] ^ cbw) & AL[3 * 128 + w]);
        }
        P[(h * 2 + 0) * 256 + m] = pa0;
        P[(h * 2 + 1) * 256 + m] = pa1;
      }
      __syncthreads();
      if (tl < 256) {
        const int m = tl;
        const int a0 = P[0 * 256 + m] + P[2 * 256 + m];
        const int a1 = P[1 * 256 + m] + P[3 * 256 + m];
        const int sim0 = C0[0] - 2 * a0;
        const int sim1 = C0[1] - 2 * a1;
        int d1 = (sim0 + 128) >> 8; int d0v = sim0 - (d1 << 8);
        stg[m] = (i8)d0v; stg[256 + m] = (i8)d1;
        d1 = (sim1 + 128) >> 8; d0v = sim1 - (d1 << 8);
        stg[768 + m] = (i8)d0v; stg[768 + 256 + m] = (i8)d1;
      }
      __syncthreads();
      if (tl < 192) {                       // coherent u64 publish of both b's digit planes
        const int bl = tl >= 96;
        const int off = tl - bl * 96;
        const u64 val = ((const u64*)stg)[bl * 96 + off];
        astore(simx64 + ((size_t)((b0 + bl) * 4 + f)) * 96 + off, val);
      }
    }
    gridbar(bar, t);

    // ---- phase B: MFMA stage-B from LDS weights (4 btiles; 4 subs of 256 thr) ----
    if (active) {
      const int sub = t >> 8;             // btile 0..3
      const int tl = t & 255;
      const int f = f_own;
      const int b0 = sub * 64;
      const int wv = tl >> 6;
      const int wrow = (wv >> 1) * 32;
      const int wcol = (wv & 1) * 64;

      v4i acc[2][2][4];
      #pragma unroll
      for (int pp = 0; pp < 2; ++pp)
        #pragma unroll
        for (int tr = 0; tr < 2; ++tr)
          #pragma unroll
          for (int tc = 0; tc < 4; ++tc) acc[pp][tr][tc] = 0;

      const int rsel = lane & 15;
      const int kq8 = (lane >> 4);        // u64 index within 32B k-chunk
      const int tb = wcol >> 4;

      #pragma unroll
      for (int ks = 0; ks < 8; ++ks) {
        long bfv[4];
        #pragma unroll
        for (int tc = 0; tc < 4; ++tc)
          bfv[tc] = *(const long*)&lS[((ks * 8 + tb + tc) * 64 + lane) * 8];
        #pragma unroll
        for (int pp = 0; pp < 2; ++pp) {
          long af[2];
          #pragma unroll
          for (int tr = 0; tr < 2; ++tr) {
            const int row = b0 + wrow + tr * 16 + rsel;
            af[tr] = (long)aload(simx64 + ((size_t)(row * 4 + f)) * 96 + pp * 32 + ks * 4 + kq8);
          }
          #pragma unroll
          for (int tr = 0; tr < 2; ++tr)
            #pragma unroll
            for (int tc = 0; tc < 4; ++tc)
              acc[pp][tr][tc] = __builtin_amdgcn_mfma_i32_16x16x32_i8(af[tr], bfv[tc], acc[pp][tr][tc], 0, 0, 0);
        }
      }

      bool chl = false;
      #pragma unroll
      for (int tr = 0; tr < 2; ++tr) {
        u64 bs[4][4], bz[4][4];
        #pragma unroll
        for (int rr = 0; rr < 4; ++rr)
          #pragma unroll
          for (int tc = 0; tc < 4; ++tc) {
            const int o = acc[0][tr][tc][rr] + acc[1][tr][tc][rr] * 256;
            bs[rr][tc] = __ballot(o < 0);
            bz[rr][tc] = __ballot(o == 0);
          }
        u64 ws = 0, wz = 0;
        #pragma unroll
        for (int rl = 0; rl < 16; ++rl) {
          const int g = rl >> 2, rr = rl & 3;
          u64 vs = 0, vz = 0;
          #pragma unroll
          for (int tc = 0; tc < 4; ++tc) {
            vs |= ((bs[rr][tc] >> (g * 16)) & 0xFFFFull) << (tc * 16);
            vz |= ((bz[rr][tc] >> (g * 16)) & 0xFFFFull) << (tc * 16);
          }
          if (lane == rl) { ws = vs; wz = vz; }
        }
        if (lane < 16) {
          const int row = b0 + wrow + tr * 16 + lane;
          const size_t wi = ((size_t)(row * 4 + f)) * 128 + (dt_own << 1) + (wcol >> 6);
          const u64 oldS = aload(esb + wi);
          const u64 oldZ = aload(ezb + wi);
          chl |= (ws != oldS) | (wz != oldZ);
          astore(esb + wi, ws);
          astore(ezb + wi, wz);
        }
      }
      if (chl) atomicOr(&chgf, 1);
      __syncthreads();
      if (t == 0 && chgf) atomicOr(&chg[it], 1);
    }
    gridbar(bar, t);
  }

  // ---- final: sim + argmax + k (512 units; 2 per block) ----
  {
    const int sub = t >> 9;
    const int tl = t & 511;
    u64* AL = (u64*)(lS + 32768 + sub * 12800);
    int* C0 = (int*)(lS + 32768 + sub * 12800 + 4096);
    int* P  = (int*)(lS + 32768 + sub * 12800 + 4224);
    long long* red0 = (long long*)(lS + 32768 + sub * 12800 + 8320);
    long long* red1 = (long long*)(lS + 32768 + sub * 12800 + 10368);
    const int unit = bid * 2 + sub;
    const int f = unit & 3;
    const int b0 = (unit >> 2) * 2;
    if (tl < 2) C0[tl] = 0;
    __syncthreads();
    if (tl < 256) {
      const int r = tl >> 7, w = tl & 127;
      const int b = b0 + r;
      const size_t a = ((size_t)b * 4 + f) * 128 + w;
      const u64 s = aload(esb + a);
      const u64 z = ~aload(ezb + a);
      AL[(r * 2 + 0) * 128 + w] = s;
      AL[(r * 2 + 1) * 128 + w] = z;
      int pcv = (int)__popcll(z);
      #pragma unroll
      for (int off = 32; off >= 1; off >>= 1) pcv += __shfl_down(pcv, off);
      if (lane == 0) atomicAdd(&C0[r], pcv);
    }
    __syncthreads();
    {
      const int h = tl >> 8;
      const int m = tl & 255;
      int pa0 = 0, pa1 = 0;
      const u64* pc = cbbT + (size_t)f * 32768 + m;
      const int w0 = h * 64;
      #pragma unroll 4
      for (int w = w0; w < w0 + 64; ++w) {
        const u64 cbw = pc[w * 256];
        pa0 += (int)__popcll((AL[0 * 128 + w] ^ cbw) & AL[1 * 128 + w]);
        pa1 += (int)__popcll((AL[2 * 128 + w] ^ cbw) & AL[3 * 128 + w]);
      }
      P[(h * 2 + 0) * 256 + m] = pa0;
      P[(h * 2 + 1) * 256 + m] = pa1;
    }
    __syncthreads();
    if (tl < 256) {
      const int m = tl;
      const int a0 = P[0 * 256 + m] + P[2 * 256 + m];
      const int a1 = P[1 * 256 + m] + P[3 * 256 + m];
      const int sim0 = C0[0] - 2 * a0;
      const int sim1 = C0[1] - 2 * a1;
      red0[m] = ((long long)sim0 << 32) | (long long)(unsigned)(255 - m);
      red1[m] = ((long long)sim1 << 32) | (long long)(unsigned)(255 - m);
    }
    __syncthreads();
    for (int s2 = 128; s2 > 0; s2 >>= 1) {
      if (tl < s2) {
        if (red0[tl + s2] > red0[tl]) red0[tl] = red0[tl + s2];
        if (red1[tl + s2] > red1[tl]) red1[tl] = red1[tl + s2];
      }
      __syncthreads();
    }
    if (tl == 0) {
      out[b0 * 4 + f] = 255 - (int)(red0[0] & 0xFFFF);
      out[(b0 + 1) * 4 + f] = 255 - (int)(red1[0] & 0xFFFF);
      if (unit == 0) {
        int k = NITER;
        for (int i = 1; i <= NITER; ++i)
          if (__hip_atomic_load(&chg[i], __ATOMIC_RELAXED, __HIP_MEMORY_SCOPE_AGENT) == 0) { k = i; break; }
        out[B_SZ * F_SZ] = k;
      }
    }
  }
}

// ---------------- host ----------------

extern "C" void kernel_launch(void* const* d_in, const int* in_sizes, int n_in,
                              void* d_out, int out_size, void* d_ws, size_t ws_size,
                              hipStream_t stream) {
  const float* f_in = (const float*)d_in[0];   // [B][D]
  const float* f_cb = (const float*)d_in[1];   // [F][M][D]
  int* out = (int*)d_out;
  char* ws = (char*)d_ws;

  i8*  cb8  = (i8*)(ws + OFF_CB);
  i8*  cbt8 = (i8*)(ws + OFF_CBT);
  i8*  in8  = (i8*)(ws + OFF_IN8);
  u64* cbbT = (u64*)(ws + OFF_CBBT);
  u64* inb  = (u64*)(ws + OFF_INB);
  u64* esb  = (u64*)(ws + OFF_ESB);
  u64* ezb  = (u64*)(ws + OFF_EZB);
  i8*  simx = (i8*)(ws + OFF_SIMX);
  int* p1   = (int*)(ws + OFF_P1);
  u64* cbtF = (u64*)(ws + OFF_CBTF);   // aliases p1 (p1 dead after k_digits1)
  int* S32  = (int*)(ws + OFF_S32);
  int* chg  = (int*)(ws + OFF_CHG);
  int* bar  = (int*)(ws + OFF_BAR);
  i8*  pdig = (i8*)(ws + OFF_PDIG);

  // zero S32 (atomic target) + chg flags + barrier state in one memset
  hipMemsetAsync(ws + OFF_S32, 0, 131072 + 128, stream);
  k_prep_cb<<<dim3(8192), dim3(256), 0, stream>>>(f_cb, cb8, cbt8, cbbT, S32);
  k_prep_in<<<dim3(2048), dim3(256), 0, stream>>>(f_in, in8, inb);
  k_P<<<dim3(32), dim3(256), 0, stream>>>(S32, pdig);

  // iteration 1 (big-integer est0 via P/8 digit planes, MFMA)
  ga2_kernel<<<dim3(768), dim3(256), 0, stream>>>(in8, cb8, pdig, p1);
  k_digits1<<<dim3(1024), dim3(256), 0, stream>>>(p1, simx);
  gb_first<<<dim3(1024), dim3(256), 0, stream>>>(simx, cbt8, esb, ezb, S32, chg, cbtF);

  // iterations 2..10 + final argmax in one fence-free persistent kernel
  k_persist<<<dim3(256), dim3(1024), 0, stream>>>(esb, ezb, inb, cbbT, cbtF,
                                                  (u64*)simx, chg, bar, out);
}